// Round 12
// baseline (175.598 us; speedup 1.0000x reference)
//
#include <hip/hip_runtime.h>
#include <hip/hip_bf16.h>
#include <cstdint>

#define NEGV (-10000.0f)

typedef short bf16x8 __attribute__((ext_vector_type(8)));
typedef short bf16x4 __attribute__((ext_vector_type(4)));
typedef float f32x4 __attribute__((ext_vector_type(4)));

__device__ __forceinline__ short f2bf(float f) {
  union { float f; uint32_t u; } v; v.f = f;
  uint32_t u = v.u + 0x7fffu + ((v.u >> 16) & 1u);
  return (short)(u >> 16);
}
__device__ __forceinline__ float b2f(short s) {
  union { uint32_t u; float f; } v; v.u = ((uint32_t)(uint16_t)s) << 16;
  return v.f;
}
__device__ __forceinline__ uint32_t pk2(float lo, float hi) {
  union { __hip_bfloat162 h2; uint32_t u; } cv;
  cv.h2.x = __float2bfloat16(lo);
  cv.h2.y = __float2bfloat16(hi);
  return cv.u;
}

// LDS-only barrier (R11): no vmcnt drain; in-flight global prefetches survive.
__device__ __forceinline__ void bar() {
  __builtin_amdgcn_sched_barrier(0);
  asm volatile("s_waitcnt lgkmcnt(0)" ::: "memory");
  __builtin_amdgcn_s_barrier();
  __builtin_amdgcn_sched_barrier(0);
}

// ---------------- P1: weight combine + bf16 casts ----------------
__global__ void prep_weights(const float* __restrict__ W1, const float* __restrict__ W2,
                             short* __restrict__ Wk, short* __restrict__ Wd,
                             short* __restrict__ W2b) {
  int idx = blockIdx.x * 256 + threadIdx.x;
  if (idx < 32768) {
    int h = idx >> 7, d = idx & 127;
    Wk[idx] = f2bf(W1[h * 512 + 128 + d] - W1[h * 512 + 256 + d]);
  } else if (idx < 65536) {
    int i = idx - 32768;
    int h = i >> 7, d = i & 127;
    Wd[i] = f2bf(W1[h * 512 + 384 + d]);
  } else {
    int i = idx - 65536;
    W2b[i] = f2bf(W2[i]);
  }
}

// ---------------- P2: U[b][h] = b1[h] + sum_d (W1[h][d]+W1[h][256+d]) * q[b][d] ----
__global__ void prep_u(const float* __restrict__ query, const float* __restrict__ W1,
                       const float* __restrict__ b1, float* __restrict__ U) {
  __shared__ float q8[8][128];
  int tid = threadIdx.x;
  int b0 = blockIdx.x * 8;
  for (int i = tid; i < 1024; i += 256)
    q8[i >> 7][i & 127] = query[(size_t)(b0 + (i >> 7)) * 128 + (i & 127)];
  __syncthreads();
  int h = tid;
  const float4* w0 = (const float4*)(W1 + (size_t)h * 512);
  const float4* w1 = (const float4*)(W1 + (size_t)h * 512 + 256);
  float acc[8];
  float bb = b1[h];
#pragma unroll
  for (int i = 0; i < 8; ++i) acc[i] = bb;
  for (int d4 = 0; d4 < 32; ++d4) {
    float4 wa = w0[d4], wb = w1[d4];
    float wv0 = wa.x + wb.x, wv1 = wa.y + wb.y, wv2 = wa.z + wb.z, wv3 = wa.w + wb.w;
#pragma unroll
    for (int i = 0; i < 8; ++i) {
      float4 qv = ((const float4*)q8[i])[d4];
      acc[i] += wv0 * qv.x + wv1 * qv.y + wv2 * qv.z + wv3 * qv.w;
    }
  }
#pragma unroll
  for (int i = 0; i < 8; ++i) U[(size_t)(b0 + i) * 256 + h] = acc[i];
}

// ---------------- fused: one 1024-thr block per b, 64-l phases ----------------
// R12: waves/CU hard-capped at 16 (metadata law) -> widen the overlap window:
// 5 phase-slots of 64 l (vs 8 of 32), staging spread over all 1024 threads,
// Kall write-once 256 rows, H1 64-row dbuf. LDS ~141 KB, 1 block/CU.
__global__ __launch_bounds__(1024) void din_fused(
    const float* __restrict__ query, const float* __restrict__ keys,
    const int* __restrict__ mask,
    const float* __restrict__ b2p, const float* __restrict__ a1p,
    const float* __restrict__ a2p, const float* __restrict__ W3,
    const float* __restrict__ U, const short* __restrict__ Wk,
    const short* __restrict__ Wd, const short* __restrict__ W2b,
    float* __restrict__ out) {
  __shared__ short Kall[256 * 128];   // 64 KB bf16 keys, XOR-swizzled, write-once
  __shared__ short H1[2][64 * 256];   // 64 KB h1 dbuf [l][h], XOR-swizzled
  __shared__ float wred[8][256];      // 8 KB per-G2-wave score partials
  __shared__ float wl[256];
  __shared__ float red[16];
  __shared__ float opart[8][128];

  const int tid = threadIdx.x;
  const int b = blockIdx.x;
  const int lane = tid & 63, wid = tid >> 6;  // 16 waves
  const int lr = lane & 15, lg = lane >> 4;
  const bool isG1 = wid < 8;
  const int sw = (lr & 7) << 3;

  bf16x8 frag[8];
  f32x4 accA, accB;
  float uv0[4], uv1[4];
  float alpha;

  if (isG1) {
    alpha = a1p[0];
    const float* qrow = query + (size_t)b * 128;
#pragma unroll
    for (int nt = 0; nt < 2; ++nt) {
      int h = wid * 32 + nt * 16 + lr;
#pragma unroll
      for (int ks = 0; ks < 4; ++ks) {
        int d0 = ks * 32 + lg * 8;
        bf16x8 wk = *(const bf16x8*)(Wk + h * 128 + d0);
        bf16x8 wd = *(const bf16x8*)(Wd + h * 128 + d0);
        float4 q0 = *(const float4*)(qrow + d0);
        float4 q1 = *(const float4*)(qrow + d0 + 4);
        float qv[8] = {q0.x, q0.y, q0.z, q0.w, q1.x, q1.y, q1.z, q1.w};
        float mv[8];
#pragma unroll
        for (int j = 0; j < 8; ++j) mv[j] = b2f(wk[j]) + b2f(wd[j]) * qv[j];
        union { bf16x8 v; uint32_t u[4]; } mm;
#pragma unroll
        for (int j = 0; j < 4; ++j) mm.u[j] = pk2(mv[2 * j], mv[2 * j + 1]);
        frag[nt * 4 + ks] = mm.v;
      }
    }
#pragma unroll
    for (int r = 0; r < 4; ++r) {
      uv0[r] = U[(size_t)b * 256 + wid * 32 + lg * 4 + r];
      uv1[r] = U[(size_t)b * 256 + wid * 32 + 16 + lg * 4 + r];
    }
  } else {
    alpha = a2p[0];
    int g = (wid - 8) * 16 + lr;
#pragma unroll
    for (int ks = 0; ks < 8; ++ks)
      frag[ks] = *(const bf16x8*)(W2b + g * 256 + ks * 32 + lg * 8);
#pragma unroll
    for (int r = 0; r < 4; ++r) {
      int gg = (wid - 8) * 16 + lg * 4 + r;
      uv0[r] = b2p[gg];
      uv1[r] = W3[gg];
    }
  }

  // staging geometry: ALL 1024 threads; 64-row tile, 16 thr/row, 8 f32 each
  const int srow = tid >> 4;          // 0..63
  const int scol = (tid & 15) * 8;    // 0..120 (shorts/floats)
  const int ssw = (srow & 7) << 3;

  // prologue: stage tiles 0,1 (rows 0..127, all valid)
  {
#pragma unroll
    for (int t = 0; t < 2; ++t) {
      int row = t * 64 + srow;
      const float4* kp4 = (const float4*)(keys + ((size_t)b * 200 + row) * 128 + scol);
      float4 x0 = kp4[0], x1 = kp4[1];
      union { bf16x8 v; uint32_t u[4]; } w;
      w.u[0] = pk2(x0.x, x0.y); w.u[1] = pk2(x0.z, x0.w);
      w.u[2] = pk2(x1.x, x1.y); w.u[3] = pk2(x1.z, x1.w);
      *(bf16x8*)(&Kall[row * 128 + (scol ^ ssw)]) = w.v;
    }
  }
  bar();

  // ---- 5 phase-slots: G1 computes tile p (p<4); G2 computes tile p-1 (p>=1);
  //      tiles 2,3 staged during phases 0,1 (issue early, write late) ----
  for (int p = 0; p < 5; ++p) {
    const int buf = p & 1;

    // issue next-stage global loads early (tiles 2,3 during p=0,1)
    float4 r0, r1;
    const bool lv = (p < 2);
    if (lv) {
      int row = (p + 2) * 64 + srow;
      r0 = r1 = make_float4(0.f, 0.f, 0.f, 0.f);
      if (row < 200) {
        const float4* kp4 = (const float4*)(keys + ((size_t)b * 200 + row) * 128 + scol);
        r0 = kp4[0]; r1 = kp4[1];
      }
    }

    if (isG1) {
      if (p < 4) {
#pragma unroll
        for (int s = 0; s < 4; ++s) {
          const int row = p * 64 + s * 16 + lr;
          bf16x8 kf[4];
#pragma unroll
          for (int ks = 0; ks < 4; ++ks)
            kf[ks] = *(const bf16x8*)(&Kall[row * 128 + ((ks * 32 + lg * 8) ^ sw)]);
#pragma unroll
          for (int r = 0; r < 4; ++r) { accA[r] = uv0[r]; accB[r] = uv1[r]; }
          __builtin_amdgcn_s_setprio(1);
#pragma unroll
          for (int ks = 0; ks < 4; ++ks) {
            accA = __builtin_amdgcn_mfma_f32_16x16x32_bf16(frag[ks], kf[ks], accA, 0, 0, 0);
            accB = __builtin_amdgcn_mfma_f32_16x16x32_bf16(frag[4 + ks], kf[ks], accB, 0, 0, 0);
          }
          __builtin_amdgcn_s_setprio(0);
          float v0, v1, v2, v3;
          union { bf16x4 v; uint32_t u[2]; } hh;
          short* h1row = &H1[buf][(s * 16 + lr) * 256];
          v0 = accA[0]; v1 = accA[1]; v2 = accA[2]; v3 = accA[3];
          v0 = (v0 >= 0.f) ? v0 : alpha * v0;
          v1 = (v1 >= 0.f) ? v1 : alpha * v1;
          v2 = (v2 >= 0.f) ? v2 : alpha * v2;
          v3 = (v3 >= 0.f) ? v3 : alpha * v3;
          hh.u[0] = pk2(v0, v1); hh.u[1] = pk2(v2, v3);
          *(bf16x4*)(&h1row[(wid * 32 + lg * 4) ^ sw]) = hh.v;
          v0 = accB[0]; v1 = accB[1]; v2 = accB[2]; v3 = accB[3];
          v0 = (v0 >= 0.f) ? v0 : alpha * v0;
          v1 = (v1 >= 0.f) ? v1 : alpha * v1;
          v2 = (v2 >= 0.f) ? v2 : alpha * v2;
          v3 = (v3 >= 0.f) ? v3 : alpha * v3;
          hh.u[0] = pk2(v0, v1); hh.u[1] = pk2(v2, v3);
          *(bf16x4*)(&h1row[(wid * 32 + 16 + lg * 4) ^ sw]) = hh.v;
        }
      }
    } else {
      if (p >= 1) {                   // GEMM2 on tile p-1 from H1[buf^1]
        const short* h1b = H1[buf ^ 1];
#pragma unroll
        for (int s = 0; s < 4; ++s) {
#pragma unroll
          for (int r = 0; r < 4; ++r) accA[r] = uv0[r];
          const short* hr = &h1b[(s * 16 + lr) * 256];
          __builtin_amdgcn_s_setprio(1);
#pragma unroll
          for (int ks = 0; ks < 8; ++ks) {
            bf16x8 hf = *(const bf16x8*)(&hr[(ks * 32 + lg * 8) ^ sw]);
            accA = __builtin_amdgcn_mfma_f32_16x16x32_bf16(frag[ks], hf, accA, 0, 0, 0);
          }
          __builtin_amdgcn_s_setprio(0);
          float sc = 0.f;
#pragma unroll
          for (int r = 0; r < 4; ++r) {
            float v = accA[r];
            v = (v >= 0.f) ? v : alpha * v;
            sc += v * uv1[r];
          }
          sc += __shfl_xor(sc, 16);
          sc += __shfl_xor(sc, 32);
          if (lg == 0) wred[wid - 8][(p - 1) * 64 + s * 16 + lr] = sc;
        }
      }
    }

    // late LDS write of staged tile (loads ~1 phase old by now)
    if (lv) {
      int row = (p + 2) * 64 + srow;
      union { bf16x8 v; uint32_t u[4]; } w;
      w.u[0] = pk2(r0.x, r0.y); w.u[1] = pk2(r0.z, r0.w);
      w.u[2] = pk2(r1.x, r1.y); w.u[3] = pk2(r1.z, r1.w);
      *(bf16x8*)(&Kall[row * 128 + (scol ^ ssw)]) = w.v;
    }
    bar();
  }

  // ---- score merge ----
  if (tid < 256) {
    float s = 0.f;
#pragma unroll
    for (int w = 0; w < 8; ++w) s += wred[w][tid];
    wl[tid] = s;
  }
  bar();

  // ---- masked softmax over l=0..199 ----
  float val = NEGV;
  int mk = 0;
  if (tid < 200) {
    mk = mask[(size_t)b * 200 + tid];
    val = mk ? wl[tid] : NEGV;
  }
  float m = val;
#pragma unroll
  for (int off = 1; off < 64; off <<= 1) m = fmaxf(m, __shfl_xor(m, off));
  if (lane == 0) red[wid] = m;
  bar();
  float smax = red[0];
#pragma unroll
  for (int i = 1; i < 16; ++i) smax = fmaxf(smax, red[i]);
  float pex = (tid < 200 && mk) ? __expf(val - smax) : 0.f;
  float s = pex;
#pragma unroll
  for (int off = 1; off < 64; off <<= 1) s += __shfl_xor(s, off);
  bar();
  if (lane == 0) red[wid] = s;
  bar();
  float ssum = 0.f;
#pragma unroll
  for (int i = 0; i < 16; ++i) ssum += red[i];
  float winv = (ssum > 0.f) ? 1.f / ssum : 0.f;
  if (tid < 256) wl[tid] = (tid < 200) ? pex * winv : 0.f;
  bar();

  // ---- weighted sum from LDS bf16 keys ----
  {
    const int d = tid & 127, slice = tid >> 7;  // 8 slices
    float acc = 0.f;
    for (int l = slice; l < 200; l += 8) {
      float wv = wl[l];
      acc += wv * b2f(Kall[l * 128 + (d ^ ((l & 7) << 3))]);
    }
    opart[slice][d] = acc;
  }
  bar();
  if (tid < 128) {
    float acc = 0.f;
#pragma unroll
    for (int i = 0; i < 8; ++i) acc += opart[i][tid];
    out[(size_t)b * 128 + tid] = acc;
  }
}

extern "C" void kernel_launch(void* const* d_in, const int* in_sizes, int n_in,
                              void* d_out, int out_size, void* d_ws, size_t ws_size,
                              hipStream_t stream) {
  const float* query = (const float*)d_in[0];
  const float* keys  = (const float*)d_in[1];
  const int*   maskp = (const int*)d_in[2];
  const float* W1    = (const float*)d_in[3];
  const float* b1    = (const float*)d_in[4];
  const float* a1    = (const float*)d_in[5];
  const float* W2    = (const float*)d_in[6];
  const float* b2    = (const float*)d_in[7];
  const float* a2    = (const float*)d_in[8];
  const float* W3    = (const float*)d_in[9];
  float* out = (float*)d_out;

  float* U   = (float*)d_ws;                         // 2 MiB
  short* Wk  = (short*)((char*)d_ws + 2097152);      // 64 KiB
  short* Wd  = Wk + 32768;                           // 64 KiB
  short* W2b = Wd + 32768;                           // 64 KiB

  prep_weights<<<384, 256, 0, stream>>>(W1, W2, Wk, Wd, W2b);
  prep_u<<<256, 256, 0, stream>>>(query, W1, b1, U);
  din_fused<<<2048, 1024, 0, stream>>>(query, keys, maskp, b2, a1, a2, W3,
                                       U, Wk, Wd, W2b, out);
}

// Round 13
// 153.043 us; speedup vs baseline: 1.1474x; 1.1474x over previous
//
#include <hip/hip_runtime.h>
#include <hip/hip_bf16.h>
#include <cstdint>

#define NEGV (-10000.0f)

typedef short bf16x8 __attribute__((ext_vector_type(8)));
typedef short bf16x4 __attribute__((ext_vector_type(4)));
typedef float f32x4 __attribute__((ext_vector_type(4)));

__device__ __forceinline__ short f2bf(float f) {
  union { float f; uint32_t u; } v; v.f = f;
  uint32_t u = v.u + 0x7fffu + ((v.u >> 16) & 1u);
  return (short)(u >> 16);
}
__device__ __forceinline__ float b2f(short s) {
  union { uint32_t u; float f; } v; v.u = ((uint32_t)(uint16_t)s) << 16;
  return v.f;
}
__device__ __forceinline__ uint32_t pk2(float lo, float hi) {
  union { __hip_bfloat162 h2; uint32_t u; } cv;
  cv.h2.x = __float2bfloat16(lo);
  cv.h2.y = __float2bfloat16(hi);
  return cv.u;
}

// LDS-only barrier: no vmcnt drain -> the distance-2 prefetch ring's global
// loads stay in flight across tile barriers (the whole point of the ring).
__device__ __forceinline__ void bar() {
  __builtin_amdgcn_sched_barrier(0);
  asm volatile("s_waitcnt lgkmcnt(0)" ::: "memory");
  __builtin_amdgcn_s_barrier();
  __builtin_amdgcn_sched_barrier(0);
}

// ---------------- P1: weight combine + bf16 casts ----------------
__global__ void prep_weights(const float* __restrict__ W1, const float* __restrict__ W2,
                             short* __restrict__ Wk, short* __restrict__ Wd,
                             short* __restrict__ W2b) {
  int idx = blockIdx.x * 256 + threadIdx.x;
  if (idx < 32768) {
    int h = idx >> 7, d = idx & 127;
    Wk[idx] = f2bf(W1[h * 512 + 128 + d] - W1[h * 512 + 256 + d]);
  } else if (idx < 65536) {
    int i = idx - 32768;
    int h = i >> 7, d = i & 127;
    Wd[i] = f2bf(W1[h * 512 + 384 + d]);
  } else {
    int i = idx - 65536;
    W2b[i] = f2bf(W2[i]);
  }
}

// ---------------- P2: U[b][h] = b1[h] + sum_d (W1[h][d]+W1[h][256+d]) * q[b][d] ----
__global__ void prep_u(const float* __restrict__ query, const float* __restrict__ W1,
                       const float* __restrict__ b1, float* __restrict__ U) {
  __shared__ float q8[8][128];
  int tid = threadIdx.x;
  int b0 = blockIdx.x * 8;
  for (int i = tid; i < 1024; i += 256)
    q8[i >> 7][i & 127] = query[(size_t)(b0 + (i >> 7)) * 128 + (i & 127)];
  __syncthreads();
  int h = tid;
  const float4* w0 = (const float4*)(W1 + (size_t)h * 512);
  const float4* w1 = (const float4*)(W1 + (size_t)h * 512 + 256);
  float acc[8];
  float bb = b1[h];
#pragma unroll
  for (int i = 0; i < 8; ++i) acc[i] = bb;
  for (int d4 = 0; d4 < 32; ++d4) {
    float4 wa = w0[d4], wb = w1[d4];
    float wv0 = wa.x + wb.x, wv1 = wa.y + wb.y, wv2 = wa.z + wb.z, wv3 = wa.w + wb.w;
#pragma unroll
    for (int i = 0; i < 8; ++i) {
      float4 qv = ((const float4*)q8[i])[d4];
      acc[i] += wv0 * qv.x + wv1 * qv.y + wv2 * qv.z + wv3 * qv.w;
    }
  }
#pragma unroll
  for (int i = 0; i < 8; ++i) U[(size_t)(b0 + i) * 256 + h] = acc[i];
}

// ---------------- fused main: block = b, 4 waves, 16-l tiles ----------------
// R13 = R7 structure + R8 distance-2 prefetch ring + lb(256,2) (VGPR cap 128,
// fits) + bar() (no vmcnt drain at barriers) + fused softmax/wsum tail.
__global__ __launch_bounds__(256, 2) void din_fused(
    const float* __restrict__ query, const float* __restrict__ keys,
    const int* __restrict__ mask,
    const float* __restrict__ b2p, const float* __restrict__ a1p,
    const float* __restrict__ a2p, const float* __restrict__ W3,
    const float* __restrict__ U, const short* __restrict__ Wk,
    const short* __restrict__ Wd, const short* __restrict__ W2b,
    float* __restrict__ out) {
  __shared__ short Kt[2][16 * 128];   // 8 KB streaming key tiles, XOR-swizzled
  __shared__ short H1[2][16 * 256];   // 16 KB h1 tiles, XOR-swizzled
  __shared__ float wred[4][208];      // 3.3 KB per-wave score partials
  __shared__ float Ul[256];
  __shared__ float b2l[128];
  __shared__ float w3l[128];
  __shared__ float wl[208];
  __shared__ float red[8];
  __shared__ float opart[8][128];

  const int tid = threadIdx.x;
  const int b = blockIdx.x;
  const int lane = tid & 63, wid = tid >> 6;  // 4 waves
  const int lr = lane & 15, lg = lane >> 4;

  const float a1 = a1p[0], a2 = a2p[0];

  Ul[tid] = U[(size_t)b * 256 + tid];
  if (tid < 128) { b2l[tid] = b2p[tid]; w3l[tid] = W3[tid]; }

  // ---- persistent fragments ----
  bf16x8 mf[4][4];   // GEMM1 A: M_b, wave owns 64 h
  {
    const float* qrow = query + (size_t)b * 128;
#pragma unroll
    for (int nt = 0; nt < 4; ++nt) {
      int h = wid * 64 + nt * 16 + lr;
#pragma unroll
      for (int ks = 0; ks < 4; ++ks) {
        int d0 = ks * 32 + lg * 8;
        bf16x8 wk = *(const bf16x8*)(Wk + h * 128 + d0);
        bf16x8 wd = *(const bf16x8*)(Wd + h * 128 + d0);
        float4 q0 = *(const float4*)(qrow + d0);
        float4 q1 = *(const float4*)(qrow + d0 + 4);
        float qv[8] = {q0.x, q0.y, q0.z, q0.w, q1.x, q1.y, q1.z, q1.w};
        float mv[8];
#pragma unroll
        for (int j = 0; j < 8; ++j) mv[j] = b2f(wk[j]) + b2f(wd[j]) * qv[j];
        union { bf16x8 v; uint32_t u[4]; } mm;
#pragma unroll
        for (int j = 0; j < 4; ++j) mm.u[j] = pk2(mv[2 * j], mv[2 * j + 1]);
        mf[nt][ks] = mm.v;
      }
    }
  }
  bf16x8 w2f[2][8];  // GEMM2 A: W2, wave owns 32 g
#pragma unroll
  for (int nt2 = 0; nt2 < 2; ++nt2) {
    int g = wid * 32 + nt2 * 16 + lr;
#pragma unroll
    for (int ks = 0; ks < 8; ++ks)
      w2f[nt2][ks] = *(const bf16x8*)(W2b + g * 256 + ks * 32 + lg * 8);
  }

  // staging geometry: 16 thr/row, 8 f32 (32B) per thread
  const int srow = tid >> 4;          // 0..15
  const int scol = (tid & 15) * 8;    // 0..120
  const int ssw = (srow & 7) << 3;

  float4 h0a, h0b;                    // ring hold: tile t+1
  {
    // tile 0 staged directly
    const float4* kp4 = (const float4*)(keys + ((size_t)b * 200 + srow) * 128 + scol);
    float4 s0 = kp4[0], s1 = kp4[1];
    union { bf16x8 v; uint32_t u[4]; } w;
    w.u[0] = pk2(s0.x, s0.y); w.u[1] = pk2(s0.z, s0.w);
    w.u[2] = pk2(s1.x, s1.y); w.u[3] = pk2(s1.z, s1.w);
    *(bf16x8*)(&Kt[0][srow * 128 + (scol ^ ssw)]) = w.v;
    // tile 1 into ring
    const float4* kp4b = (const float4*)(keys + ((size_t)b * 200 + 16 + srow) * 128 + scol);
    h0a = kp4b[0]; h0b = kp4b[1];
  }
  bar();

  // ---- 13 tiles of 16 l (tile 12: rows 192..199 + 8 zero rows) ----
  for (int t = 0; t < 13; ++t) {
    const int buf = t & 1;

    // issue loads for tile t+2 (~1.5 tiles in flight; survive bar())
    float4 n0, n1;
    if (t < 11) {
      int gl = (t + 2) * 16 + srow;
      n0 = n1 = make_float4(0.f, 0.f, 0.f, 0.f);
      if (gl < 200) {
        const float4* kp4 = (const float4*)(keys + ((size_t)b * 200 + gl) * 128 + scol);
        n0 = kp4[0]; n1 = kp4[1];
      }
    }

    // GEMM1: D[h][l] = M_b · K^T
    const int sw = (lr & 7) << 3;
    bf16x8 kf[4];
#pragma unroll
    for (int ks = 0; ks < 4; ++ks)
      kf[ks] = *(const bf16x8*)(&Kt[buf][lr * 128 + ((ks * 32 + lg * 8) ^ sw)]);
    f32x4 acc[4];
#pragma unroll
    for (int nt = 0; nt < 4; ++nt)
#pragma unroll
      for (int r = 0; r < 4; ++r) acc[nt][r] = Ul[wid * 64 + nt * 16 + lg * 4 + r];
    __builtin_amdgcn_s_setprio(1);
#pragma unroll
    for (int ks = 0; ks < 4; ++ks)
#pragma unroll
      for (int nt = 0; nt < 4; ++nt)
        acc[nt] = __builtin_amdgcn_mfma_f32_16x16x32_bf16(mf[nt][ks], kf[ks], acc[nt], 0, 0, 0);
    __builtin_amdgcn_s_setprio(0);
    // PReLU(a1) -> H1[buf][lr][h]
    short* h1b = H1[buf];
#pragma unroll
    for (int nt = 0; nt < 4; ++nt) {
      float v0 = acc[nt][0], v1 = acc[nt][1], v2 = acc[nt][2], v3 = acc[nt][3];
      v0 = (v0 >= 0.f) ? v0 : a1 * v0;
      v1 = (v1 >= 0.f) ? v1 : a1 * v1;
      v2 = (v2 >= 0.f) ? v2 : a1 * v2;
      v3 = (v3 >= 0.f) ? v3 : a1 * v3;
      union { bf16x4 v; uint32_t u[2]; } hh;
      hh.u[0] = pk2(v0, v1); hh.u[1] = pk2(v2, v3);
      int h0 = wid * 64 + nt * 16 + lg * 4;
      *(bf16x4*)(&h1b[lr * 256 + (h0 ^ sw)]) = hh.v;
    }

    // write tile t+1 (held in ring since t-1) -> other Kt buffer
    if (t < 12) {
      union { bf16x8 v; uint32_t u[4]; } w;
      w.u[0] = pk2(h0a.x, h0a.y); w.u[1] = pk2(h0a.z, h0a.w);
      w.u[2] = pk2(h0b.x, h0b.y); w.u[3] = pk2(h0b.z, h0b.w);
      *(bf16x8*)(&Kt[buf ^ 1][srow * 128 + (scol ^ ssw)]) = w.v;
    }
    bar();  // LDS-only: t+2 loads stay in flight

    // GEMM2: D[g][l] = W2 · H1^T
    f32x4 acc2[2];
#pragma unroll
    for (int nt2 = 0; nt2 < 2; ++nt2)
#pragma unroll
      for (int r = 0; r < 4; ++r) acc2[nt2][r] = b2l[wid * 32 + nt2 * 16 + lg * 4 + r];
    __builtin_amdgcn_s_setprio(1);
#pragma unroll
    for (int ks = 0; ks < 8; ++ks) {
      bf16x8 hf = *(const bf16x8*)(&h1b[lr * 256 + ((ks * 32 + lg * 8) ^ sw)]);
      acc2[0] = __builtin_amdgcn_mfma_f32_16x16x32_bf16(w2f[0][ks], hf, acc2[0], 0, 0, 0);
      acc2[1] = __builtin_amdgcn_mfma_f32_16x16x32_bf16(w2f[1][ks], hf, acc2[1], 0, 0, 0);
    }
    __builtin_amdgcn_s_setprio(0);
    float s = 0.f;
#pragma unroll
    for (int nt2 = 0; nt2 < 2; ++nt2)
#pragma unroll
      for (int r = 0; r < 4; ++r) {
        float v = acc2[nt2][r];
        v = (v >= 0.f) ? v : a2 * v;
        s += v * w3l[wid * 32 + nt2 * 16 + lg * 4 + r];
      }
    s += __shfl_xor(s, 16);
    s += __shfl_xor(s, 32);
    if (lg == 0) wred[wid][t * 16 + lr] = s;

    if (t < 11) { h0a = n0; h0b = n1; }
  }
  bar();

  // ---- masked softmax over l=0..199 ----
  float val = NEGV;
  int mk = 0;
  if (tid < 200) {
    mk = mask[(size_t)b * 200 + tid];
    float sc = wred[0][tid] + wred[1][tid] + wred[2][tid] + wred[3][tid];
    val = mk ? sc : NEGV;
  }
  float m = val;
#pragma unroll
  for (int off = 1; off < 64; off <<= 1) m = fmaxf(m, __shfl_xor(m, off));
  if (lane == 0) red[wid] = m;
  bar();
  float smax = fmaxf(fmaxf(red[0], red[1]), fmaxf(red[2], red[3]));
  float pex = (tid < 200 && mk) ? __expf(val - smax) : 0.f;
  float s = pex;
#pragma unroll
  for (int off = 1; off < 64; off <<= 1) s += __shfl_xor(s, off);
  if (lane == 0) red[4 + wid] = s;
  bar();
  float ssum = red[4] + red[5] + red[6] + red[7];
  float winv = (ssum > 0.f) ? 1.f / ssum : 0.f;
  if (tid < 208) wl[tid] = (tid < 200) ? pex * winv : 0.f;
  bar();

  // ---- weighted sum from global keys (L3-hot: just read by this block) ----
  {
    const int d4 = (tid & 31) << 2;  // 0..124
    const int slice = tid >> 5;      // 0..7
    float ax = 0.f, ay = 0.f, az = 0.f, aw = 0.f;
    for (int l = slice; l < 200; l += 8) {
      float wv = wl[l];
      float4 kv = *(const float4*)(keys + ((size_t)b * 200 + l) * 128 + d4);
      ax += wv * kv.x; ay += wv * kv.y; az += wv * kv.z; aw += wv * kv.w;
    }
    *(float4*)(&opart[slice][d4]) = make_float4(ax, ay, az, aw);
  }
  __syncthreads();  // tail: drain everything before final read
  if (tid < 128) {
    float acc = 0.f;
#pragma unroll
    for (int i = 0; i < 8; ++i) acc += opart[i][tid];
    out[(size_t)b * 128 + tid] = acc;
  }
}

extern "C" void kernel_launch(void* const* d_in, const int* in_sizes, int n_in,
                              void* d_out, int out_size, void* d_ws, size_t ws_size,
                              hipStream_t stream) {
  const float* query = (const float*)d_in[0];
  const float* keys  = (const float*)d_in[1];
  const int*   maskp = (const int*)d_in[2];
  const float* W1    = (const float*)d_in[3];
  const float* b1    = (const float*)d_in[4];
  const float* a1    = (const float*)d_in[5];
  const float* W2    = (const float*)d_in[6];
  const float* b2    = (const float*)d_in[7];
  const float* a2    = (const float*)d_in[8];
  const float* W3    = (const float*)d_in[9];
  float* out = (float*)d_out;

  float* U   = (float*)d_ws;                         // 2 MiB
  short* Wk  = (short*)((char*)d_ws + 2097152);      // 64 KiB
  short* Wd  = Wk + 32768;                           // 64 KiB
  short* W2b = Wd + 32768;                           // 64 KiB

  prep_weights<<<384, 256, 0, stream>>>(W1, W2, Wk, Wd, W2b);
  prep_u<<<256, 256, 0, stream>>>(query, W1, b1, U);
  din_fused<<<2048, 256, 0, stream>>>(query, keys, maskp, b2, a1, a2, W3,
                                      U, Wk, Wd, W2b, out);
}

// Round 14
// 147.902 us; speedup vs baseline: 1.1873x; 1.0348x over previous
//
#include <hip/hip_runtime.h>
#include <hip/hip_bf16.h>
#include <cstdint>

#define NEGV (-10000.0f)

typedef short bf16x8 __attribute__((ext_vector_type(8)));
typedef short bf16x4 __attribute__((ext_vector_type(4)));
typedef float f32x4 __attribute__((ext_vector_type(4)));

__device__ __forceinline__ short f2bf(float f) {
  union { float f; uint32_t u; } v; v.f = f;
  uint32_t u = v.u + 0x7fffu + ((v.u >> 16) & 1u);
  return (short)(u >> 16);
}
__device__ __forceinline__ float b2f(short s) {
  union { uint32_t u; float f; } v; v.u = ((uint32_t)(uint16_t)s) << 16;
  return v.f;
}
__device__ __forceinline__ uint32_t pk2(float lo, float hi) {
  union { __hip_bfloat162 h2; uint32_t u; } cv;
  cv.h2.x = __float2bfloat16(lo);
  cv.h2.y = __float2bfloat16(hi);
  return cv.u;
}

// LDS-only barrier: no vmcnt drain; ring prefetch loads survive barriers.
__device__ __forceinline__ void bar() {
  __builtin_amdgcn_sched_barrier(0);
  asm volatile("s_waitcnt lgkmcnt(0)" ::: "memory");
  __builtin_amdgcn_s_barrier();
  __builtin_amdgcn_sched_barrier(0);
}

// ---------------- P1: weight combine + bf16 casts ----------------
__global__ void prep_weights(const float* __restrict__ W1, const float* __restrict__ W2,
                             short* __restrict__ Wk, short* __restrict__ Wd,
                             short* __restrict__ W2b) {
  int idx = blockIdx.x * 256 + threadIdx.x;
  if (idx < 32768) {
    int h = idx >> 7, d = idx & 127;
    Wk[idx] = f2bf(W1[h * 512 + 128 + d] - W1[h * 512 + 256 + d]);
  } else if (idx < 65536) {
    int i = idx - 32768;
    int h = i >> 7, d = i & 127;
    Wd[i] = f2bf(W1[h * 512 + 384 + d]);
  } else {
    int i = idx - 65536;
    W2b[i] = f2bf(W2[i]);
  }
}

// ---------------- P2: U[b][h] = b1[h] + sum_d (W1[h][d]+W1[h][256+d]) * q[b][d] ----
__global__ void prep_u(const float* __restrict__ query, const float* __restrict__ W1,
                       const float* __restrict__ b1, float* __restrict__ U) {
  __shared__ float q8[8][128];
  int tid = threadIdx.x;
  int b0 = blockIdx.x * 8;
  for (int i = tid; i < 1024; i += 256)
    q8[i >> 7][i & 127] = query[(size_t)(b0 + (i >> 7)) * 128 + (i & 127)];
  __syncthreads();
  int h = tid;
  const float4* w0 = (const float4*)(W1 + (size_t)h * 512);
  const float4* w1 = (const float4*)(W1 + (size_t)h * 512 + 256);
  float acc[8];
  float bb = b1[h];
#pragma unroll
  for (int i = 0; i < 8; ++i) acc[i] = bb;
  for (int d4 = 0; d4 < 32; ++d4) {
    float4 wa = w0[d4], wb = w1[d4];
    float wv0 = wa.x + wb.x, wv1 = wa.y + wb.y, wv2 = wa.z + wb.z, wv3 = wa.w + wb.w;
#pragma unroll
    for (int i = 0; i < 8; ++i) {
      float4 qv = ((const float4*)q8[i])[d4];
      acc[i] += wv0 * qv.x + wv1 * qv.y + wv2 * qv.z + wv3 * qv.w;
    }
  }
#pragma unroll
  for (int i = 0; i < 8; ++i) U[(size_t)(b0 + i) * 256 + h] = acc[i];
}

// ---------------- fused main: block = b, 4 waves, 16-l tiles, pipelined ------
// R14: GEMM2(t-1) and GEMM1(t) execute in the SAME phase (different LDS
// buffers, no dependence) -> 32 MFMA/wave/phase with independent chains and
// ONE barrier per tile. Hazards: H1[t&1] last read by GEMM2(t-2) in phase t-1;
// Kt[(t+1)&1] last read by GEMM1(t-1) in phase t-1 — one bar separates all.
__global__ __launch_bounds__(256, 2) void din_fused(
    const float* __restrict__ query, const float* __restrict__ keys,
    const int* __restrict__ mask,
    const float* __restrict__ b2p, const float* __restrict__ a1p,
    const float* __restrict__ a2p, const float* __restrict__ W3,
    const float* __restrict__ U, const short* __restrict__ Wk,
    const short* __restrict__ Wd, const short* __restrict__ W2b,
    float* __restrict__ out) {
  __shared__ short Kt[2][16 * 128];   // 8 KB streaming key tiles, XOR-swizzled
  __shared__ short H1[2][16 * 256];   // 16 KB h1 tiles, XOR-swizzled
  __shared__ float wred[4][208];      // per-wave score partials
  __shared__ float Ul[256];
  __shared__ float b2l[128];
  __shared__ float w3l[128];
  __shared__ float wl[208];
  __shared__ float red[8];
  __shared__ float opart[8][128];

  const int tid = threadIdx.x;
  const int b = blockIdx.x;
  const int lane = tid & 63, wid = tid >> 6;  // 4 waves
  const int lr = lane & 15, lg = lane >> 4;

  const float a1 = a1p[0], a2 = a2p[0];

  Ul[tid] = U[(size_t)b * 256 + tid];
  if (tid < 128) { b2l[tid] = b2p[tid]; w3l[tid] = W3[tid]; }

  // ---- persistent fragments ----
  bf16x8 mf[4][4];   // GEMM1 A: M_b, wave owns 64 h
  {
    const float* qrow = query + (size_t)b * 128;
#pragma unroll
    for (int nt = 0; nt < 4; ++nt) {
      int h = wid * 64 + nt * 16 + lr;
#pragma unroll
      for (int ks = 0; ks < 4; ++ks) {
        int d0 = ks * 32 + lg * 8;
        bf16x8 wk = *(const bf16x8*)(Wk + h * 128 + d0);
        bf16x8 wd = *(const bf16x8*)(Wd + h * 128 + d0);
        float4 q0 = *(const float4*)(qrow + d0);
        float4 q1 = *(const float4*)(qrow + d0 + 4);
        float qv[8] = {q0.x, q0.y, q0.z, q0.w, q1.x, q1.y, q1.z, q1.w};
        float mv[8];
#pragma unroll
        for (int j = 0; j < 8; ++j) mv[j] = b2f(wk[j]) + b2f(wd[j]) * qv[j];
        union { bf16x8 v; uint32_t u[4]; } mm;
#pragma unroll
        for (int j = 0; j < 4; ++j) mm.u[j] = pk2(mv[2 * j], mv[2 * j + 1]);
        mf[nt][ks] = mm.v;
      }
    }
  }
  bf16x8 w2f[2][8];  // GEMM2 A: W2, wave owns 32 g
#pragma unroll
  for (int nt2 = 0; nt2 < 2; ++nt2) {
    int g = wid * 32 + nt2 * 16 + lr;
#pragma unroll
    for (int ks = 0; ks < 8; ++ks)
      w2f[nt2][ks] = *(const bf16x8*)(W2b + g * 256 + ks * 32 + lg * 8);
  }

  // staging geometry: 16 thr/row, 8 f32 (32B) per thread
  const int srow = tid >> 4;          // 0..15
  const int scol = (tid & 15) * 8;    // 0..120
  const int ssw = (srow & 7) << 3;

  float4 h0a, h0b;                    // ring hold: tile t+1
  {
    const float4* kp4 = (const float4*)(keys + ((size_t)b * 200 + srow) * 128 + scol);
    float4 s0 = kp4[0], s1 = kp4[1];
    union { bf16x8 v; uint32_t u[4]; } w;
    w.u[0] = pk2(s0.x, s0.y); w.u[1] = pk2(s0.z, s0.w);
    w.u[2] = pk2(s1.x, s1.y); w.u[3] = pk2(s1.z, s1.w);
    *(bf16x8*)(&Kt[0][srow * 128 + (scol ^ ssw)]) = w.v;
    const float4* kp4b = (const float4*)(keys + ((size_t)b * 200 + 16 + srow) * 128 + scol);
    h0a = kp4b[0]; h0b = kp4b[1];
  }
  bar();

  const int sw = (lr & 7) << 3;

  // ---- 13 pipelined phases, 1 barrier each ----
  for (int t = 0; t < 13; ++t) {
    const int buf = t & 1;

    // issue loads for tile t+2 (survive bar(); written next phase)
    float4 n0, n1;
    if (t < 11) {
      int gl = (t + 2) * 16 + srow;
      n0 = n1 = make_float4(0.f, 0.f, 0.f, 0.f);
      if (gl < 200) {
        const float4* kp4 = (const float4*)(keys + ((size_t)b * 200 + gl) * 128 + scol);
        n0 = kp4[0]; n1 = kp4[1];
      }
    }

    // ---- GEMM2 on tile t-1 (reads H1[buf^1]; independent of GEMM1 below) ----
    if (t >= 1) {
      const short* h1p = H1[buf ^ 1];
      f32x4 acc2[2];
#pragma unroll
      for (int nt2 = 0; nt2 < 2; ++nt2)
#pragma unroll
        for (int r = 0; r < 4; ++r) acc2[nt2][r] = b2l[wid * 32 + nt2 * 16 + lg * 4 + r];
      __builtin_amdgcn_s_setprio(1);
#pragma unroll
      for (int ks = 0; ks < 8; ++ks) {
        bf16x8 hf = *(const bf16x8*)(&h1p[lr * 256 + ((ks * 32 + lg * 8) ^ sw)]);
        acc2[0] = __builtin_amdgcn_mfma_f32_16x16x32_bf16(w2f[0][ks], hf, acc2[0], 0, 0, 0);
        acc2[1] = __builtin_amdgcn_mfma_f32_16x16x32_bf16(w2f[1][ks], hf, acc2[1], 0, 0, 0);
      }
      __builtin_amdgcn_s_setprio(0);
      float s = 0.f;
#pragma unroll
      for (int nt2 = 0; nt2 < 2; ++nt2)
#pragma unroll
        for (int r = 0; r < 4; ++r) {
          float v = acc2[nt2][r];
          v = (v >= 0.f) ? v : a2 * v;
          s += v * w3l[wid * 32 + nt2 * 16 + lg * 4 + r];
        }
      s += __shfl_xor(s, 16);
      s += __shfl_xor(s, 32);
      if (lg == 0) wred[wid][(t - 1) * 16 + lr] = s;
    }

    // ---- GEMM1 on tile t (reads Kt[buf], writes H1[buf]) ----
    {
      bf16x8 kf[4];
#pragma unroll
      for (int ks = 0; ks < 4; ++ks)
        kf[ks] = *(const bf16x8*)(&Kt[buf][lr * 128 + ((ks * 32 + lg * 8) ^ sw)]);
      f32x4 acc[4];
#pragma unroll
      for (int nt = 0; nt < 4; ++nt)
#pragma unroll
        for (int r = 0; r < 4; ++r) acc[nt][r] = Ul[wid * 64 + nt * 16 + lg * 4 + r];
      __builtin_amdgcn_s_setprio(1);
#pragma unroll
      for (int ks = 0; ks < 4; ++ks)
#pragma unroll
        for (int nt = 0; nt < 4; ++nt)
          acc[nt] = __builtin_amdgcn_mfma_f32_16x16x32_bf16(mf[nt][ks], kf[ks], acc[nt], 0, 0, 0);
      __builtin_amdgcn_s_setprio(0);
      short* h1b = H1[buf];
#pragma unroll
      for (int nt = 0; nt < 4; ++nt) {
        float v0 = acc[nt][0], v1 = acc[nt][1], v2 = acc[nt][2], v3 = acc[nt][3];
        v0 = (v0 >= 0.f) ? v0 : a1 * v0;
        v1 = (v1 >= 0.f) ? v1 : a1 * v1;
        v2 = (v2 >= 0.f) ? v2 : a1 * v2;
        v3 = (v3 >= 0.f) ? v3 : a1 * v3;
        union { bf16x4 v; uint32_t u[2]; } hh;
        hh.u[0] = pk2(v0, v1); hh.u[1] = pk2(v2, v3);
        int h0 = wid * 64 + nt * 16 + lg * 4;
        *(bf16x4*)(&h1b[lr * 256 + (h0 ^ sw)]) = hh.v;
      }
    }

    // ring write: tile t+1 -> Kt[buf^1] (last read by GEMM1(t-1), pre-bar(t-1))
    if (t < 12) {
      union { bf16x8 v; uint32_t u[4]; } w;
      w.u[0] = pk2(h0a.x, h0a.y); w.u[1] = pk2(h0a.z, h0a.w);
      w.u[2] = pk2(h0b.x, h0b.y); w.u[3] = pk2(h0b.z, h0b.w);
      *(bf16x8*)(&Kt[buf ^ 1][srow * 128 + (scol ^ ssw)]) = w.v;
    }
    if (t < 11) { h0a = n0; h0b = n1; }

    bar();  // the ONLY barrier per tile
  }

  // ---- drain: GEMM2 on tile 12 (H1[0]) ----
  {
    const short* h1p = H1[0];
    f32x4 acc2[2];
#pragma unroll
    for (int nt2 = 0; nt2 < 2; ++nt2)
#pragma unroll
      for (int r = 0; r < 4; ++r) acc2[nt2][r] = b2l[wid * 32 + nt2 * 16 + lg * 4 + r];
#pragma unroll
    for (int ks = 0; ks < 8; ++ks) {
      bf16x8 hf = *(const bf16x8*)(&h1p[lr * 256 + ((ks * 32 + lg * 8) ^ sw)]);
      acc2[0] = __builtin_amdgcn_mfma_f32_16x16x32_bf16(w2f[0][ks], hf, acc2[0], 0, 0, 0);
      acc2[1] = __builtin_amdgcn_mfma_f32_16x16x32_bf16(w2f[1][ks], hf, acc2[1], 0, 0, 0);
    }
    float s = 0.f;
#pragma unroll
    for (int nt2 = 0; nt2 < 2; ++nt2)
#pragma unroll
      for (int r = 0; r < 4; ++r) {
        float v = acc2[nt2][r];
        v = (v >= 0.f) ? v : a2 * v;
        s += v * w3l[wid * 32 + nt2 * 16 + lg * 4 + r];
      }
    s += __shfl_xor(s, 16);
    s += __shfl_xor(s, 32);
    if (lg == 0) wred[wid][12 * 16 + lr] = s;
  }
  bar();

  // ---- masked softmax over l=0..199 ----
  float val = NEGV;
  int mk = 0;
  if (tid < 200) {
    mk = mask[(size_t)b * 200 + tid];
    float sc = wred[0][tid] + wred[1][tid] + wred[2][tid] + wred[3][tid];
    val = mk ? sc : NEGV;
  }
  float m = val;
#pragma unroll
  for (int off = 1; off < 64; off <<= 1) m = fmaxf(m, __shfl_xor(m, off));
  if (lane == 0) red[wid] = m;
  bar();
  float smax = fmaxf(fmaxf(red[0], red[1]), fmaxf(red[2], red[3]));
  float pex = (tid < 200 && mk) ? __expf(val - smax) : 0.f;
  float s = pex;
#pragma unroll
  for (int off = 1; off < 64; off <<= 1) s += __shfl_xor(s, off);
  if (lane == 0) red[4 + wid] = s;
  bar();
  float ssum = red[4] + red[5] + red[6] + red[7];
  float winv = (ssum > 0.f) ? 1.f / ssum : 0.f;
  if (tid < 208) wl[tid] = (tid < 200) ? pex * winv : 0.f;
  bar();

  // ---- weighted sum from global keys (L3-hot) ----
  {
    const int d4 = (tid & 31) << 2;  // 0..124
    const int slice = tid >> 5;      // 0..7
    float ax = 0.f, ay = 0.f, az = 0.f, aw = 0.f;
    for (int l = slice; l < 200; l += 8) {
      float wv = wl[l];
      float4 kv = *(const float4*)(keys + ((size_t)b * 200 + l) * 128 + d4);
      ax += wv * kv.x; ay += wv * kv.y; az += wv * kv.z; aw += wv * kv.w;
    }
    *(float4*)(&opart[slice][d4]) = make_float4(ax, ay, az, aw);
  }
  __syncthreads();
  if (tid < 128) {
    float acc = 0.f;
#pragma unroll
    for (int i = 0; i < 8; ++i) acc += opart[i][tid];
    out[(size_t)b * 128 + tid] = acc;
  }
}

extern "C" void kernel_launch(void* const* d_in, const int* in_sizes, int n_in,
                              void* d_out, int out_size, void* d_ws, size_t ws_size,
                              hipStream_t stream) {
  const float* query = (const float*)d_in[0];
  const float* keys  = (const float*)d_in[1];
  const int*   maskp = (const int*)d_in[2];
  const float* W1    = (const float*)d_in[3];
  const float* b1    = (const float*)d_in[4];
  const float* a1    = (const float*)d_in[5];
  const float* W2    = (const float*)d_in[6];
  const float* b2    = (const float*)d_in[7];
  const float* a2    = (const float*)d_in[8];
  const float* W3    = (const float*)d_in[9];
  float* out = (float*)d_out;

  float* U   = (float*)d_ws;                         // 2 MiB
  short* Wk  = (short*)((char*)d_ws + 2097152);      // 64 KiB
  short* Wd  = Wk + 32768;                           // 64 KiB
  short* W2b = Wd + 32768;                           // 64 KiB

  prep_weights<<<384, 256, 0, stream>>>(W1, W2, Wk, Wd, W2b);
  prep_u<<<256, 256, 0, stream>>>(query, W1, b1, U);
  din_fused<<<2048, 256, 0, stream>>>(query, keys, maskp, b2, a1, a2, W3,
                                      U, Wk, Wd, W2b, out);
}